// Round 1
// baseline (2074.253 us; speedup 1.0000x reference)
//
#include <hip/hip_runtime.h>
#include <hip/hip_bf16.h>

#define N_NODES 100000
#define N_EDGES 3200000
#define F_IN    512
#define H_DIM   64
#define C_DIM   64
#define K_STEPS 10
#define ALPHA   0.1f

// ---------------------------------------------------------------- zero
__global__ void zero_kernel(int* __restrict__ deg, int* __restrict__ cursor, int n) {
    int i = blockIdx.x * blockDim.x + threadIdx.x;
    if (i < n) { deg[i] = 0; cursor[i] = 0; }
}

// ---------------------------------------------------------------- degree (in-degree by dst)
__global__ void deg_kernel(const int* __restrict__ dst, int* __restrict__ deg, int e) {
    int i = blockIdx.x * blockDim.x + threadIdx.x;
    if (i < e) atomicAdd(&deg[dst[i]], 1);
}

// ---------------------------------------------------------------- dinv / self weight
__global__ void dinv_kernel(const int* __restrict__ deg, float* __restrict__ dinv,
                            float* __restrict__ selfw, int n) {
    int i = blockIdx.x * blockDim.x + threadIdx.x;
    if (i < n) {
        float dg = (float)deg[i] + 1.0f;
        float di = rsqrtf(dg);
        dinv[i]  = di;
        selfw[i] = di * di;
    }
}

// ---------------------------------------------------------------- exclusive scan (single block, 1024 thr)
__global__ void scan_kernel(const int* __restrict__ deg, int* __restrict__ row_start, int n) {
    __shared__ int wsum[16];
    __shared__ int carry_s;
    int tid = threadIdx.x;
    int lane = tid & 63;
    int w = tid >> 6;
    if (tid == 0) carry_s = 0;
    __syncthreads();
    for (int base = 0; base < n; base += 1024) {
        int i = base + tid;
        int v = (i < n) ? deg[i] : 0;
        int incl = v;
        #pragma unroll
        for (int off = 1; off < 64; off <<= 1) {
            int t = __shfl_up(incl, off);
            if (lane >= off) incl += t;
        }
        if (lane == 63) wsum[w] = incl;
        __syncthreads();
        int woff = 0;
        #pragma unroll
        for (int j = 0; j < 16; ++j) woff += (j < w) ? wsum[j] : 0;
        int carry = carry_s;
        if (i < n) row_start[i] = carry + woff + (incl - v);
        __syncthreads();              // all reads of carry_s/wsum done
        if (tid == 0) {
            int tot = 0;
            #pragma unroll
            for (int j = 0; j < 16; ++j) tot += wsum[j];
            carry_s += tot;
        }
        __syncthreads();              // carry update visible before next chunk
    }
    if (threadIdx.x == 0) row_start[n] = carry_s;
}

// ---------------------------------------------------------------- CSR scatter
__global__ void scatter_kernel(const int* __restrict__ src, const int* __restrict__ dst,
                               const int* __restrict__ row_start, int* __restrict__ cursor,
                               const float* __restrict__ dinv, int* __restrict__ csr_src,
                               float* __restrict__ csr_norm, int e) {
    int i = blockIdx.x * blockDim.x + threadIdx.x;
    if (i >= e) return;
    int s = src[i], d = dst[i];
    int pos = row_start[d] + atomicAdd(&cursor[d], 1);
    csr_src[pos]  = s;
    csr_norm[pos] = dinv[s] * dinv[d];
}

// ---------------------------------------------------------------- fused MLP: h = relu(x@W1^T+b1)@W2^T+b2
// W1 (64x512 fp32 = 128KB) + W2 (64x64 = 16KB) in LDS, 2 rows/thread.
__global__ __launch_bounds__(256, 1) void mlp_kernel(
    const float* __restrict__ x, const float* __restrict__ W1, const float* __restrict__ b1,
    const float* __restrict__ W2, const float* __restrict__ b2, float* __restrict__ h, int n)
{
    __shared__ float w1s[64 * 512];
    __shared__ float w2s[64 * 64];
    __shared__ float b1s[64], b2s[64];
    for (int i = threadIdx.x; i < 64 * 512; i += 256) w1s[i] = W1[i];
    for (int i = threadIdx.x; i < 64 * 64; i += 256)  w2s[i] = W2[i];
    if (threadIdx.x < 64) { b1s[threadIdx.x] = b1[threadIdx.x]; b2s[threadIdx.x] = b2[threadIdx.x]; }
    __syncthreads();

    int base = blockIdx.x * 512;
    int r0 = base + (int)threadIdx.x;
    int r1 = r0 + 256;
    bool v0 = r0 < n, v1 = r1 < n;

    float acc0[64], acc1[64];
    #pragma unroll
    for (int o = 0; o < 64; ++o) { acc0[o] = b1s[o]; acc1[o] = b1s[o]; }

    const float* xr0 = x + (size_t)r0 * F_IN;
    const float* xr1 = x + (size_t)r1 * F_IN;
    for (int k = 0; k < F_IN; k += 4) {
        float4 xv0 = v0 ? *reinterpret_cast<const float4*>(xr0 + k) : make_float4(0.f, 0.f, 0.f, 0.f);
        float4 xv1 = v1 ? *reinterpret_cast<const float4*>(xr1 + k) : make_float4(0.f, 0.f, 0.f, 0.f);
        #pragma unroll
        for (int o = 0; o < 64; ++o) {
            float4 wv = *reinterpret_cast<const float4*>(&w1s[o * F_IN + k]);
            acc0[o] += xv0.x * wv.x + xv0.y * wv.y + xv0.z * wv.z + xv0.w * wv.w;
            acc1[o] += xv1.x * wv.x + xv1.y * wv.y + xv1.z * wv.z + xv1.w * wv.w;
        }
    }
    #pragma unroll
    for (int o = 0; o < 64; ++o) { acc0[o] = fmaxf(acc0[o], 0.f); acc1[o] = fmaxf(acc1[o], 0.f); }

    if (v0) {
        float* hr = h + (size_t)r0 * C_DIM;
        #pragma unroll
        for (int c = 0; c < 64; c += 4) {
            float s0 = b2s[c], s1 = b2s[c + 1], s2 = b2s[c + 2], s3 = b2s[c + 3];
            #pragma unroll
            for (int o = 0; o < 64; o += 4) {
                float4 w0 = *reinterpret_cast<const float4*>(&w2s[(c + 0) * 64 + o]);
                float4 w1v = *reinterpret_cast<const float4*>(&w2s[(c + 1) * 64 + o]);
                float4 w2v = *reinterpret_cast<const float4*>(&w2s[(c + 2) * 64 + o]);
                float4 w3 = *reinterpret_cast<const float4*>(&w2s[(c + 3) * 64 + o]);
                s0 += acc0[o] * w0.x + acc0[o + 1] * w0.y + acc0[o + 2] * w0.z + acc0[o + 3] * w0.w;
                s1 += acc0[o] * w1v.x + acc0[o + 1] * w1v.y + acc0[o + 2] * w1v.z + acc0[o + 3] * w1v.w;
                s2 += acc0[o] * w2v.x + acc0[o + 1] * w2v.y + acc0[o + 2] * w2v.z + acc0[o + 3] * w2v.w;
                s3 += acc0[o] * w3.x + acc0[o + 1] * w3.y + acc0[o + 2] * w3.z + acc0[o + 3] * w3.w;
            }
            *reinterpret_cast<float4*>(hr + c) = make_float4(s0, s1, s2, s3);
        }
    }
    if (v1) {
        float* hr = h + (size_t)r1 * C_DIM;
        #pragma unroll
        for (int c = 0; c < 64; c += 4) {
            float s0 = b2s[c], s1 = b2s[c + 1], s2 = b2s[c + 2], s3 = b2s[c + 3];
            #pragma unroll
            for (int o = 0; o < 64; o += 4) {
                float4 w0 = *reinterpret_cast<const float4*>(&w2s[(c + 0) * 64 + o]);
                float4 w1v = *reinterpret_cast<const float4*>(&w2s[(c + 1) * 64 + o]);
                float4 w2v = *reinterpret_cast<const float4*>(&w2s[(c + 2) * 64 + o]);
                float4 w3 = *reinterpret_cast<const float4*>(&w2s[(c + 3) * 64 + o]);
                s0 += acc1[o] * w0.x + acc1[o + 1] * w0.y + acc1[o + 2] * w0.z + acc1[o + 3] * w0.w;
                s1 += acc1[o] * w1v.x + acc1[o + 1] * w1v.y + acc1[o + 2] * w1v.z + acc1[o + 3] * w1v.w;
                s2 += acc1[o] * w2v.x + acc1[o + 1] * w2v.y + acc1[o + 2] * w2v.z + acc1[o + 3] * w2v.w;
                s3 += acc1[o] * w3.x + acc1[o + 1] * w3.y + acc1[o + 2] * w3.z + acc1[o + 3] * w3.w;
            }
            *reinterpret_cast<float4*>(hr + c) = make_float4(s0, s1, s2, s3);
        }
    }
}

// ---------------------------------------------------------------- one APPNP step: wave per node, lane = channel
__global__ __launch_bounds__(256) void appnp_kernel(
    const int* __restrict__ row_start, const int* __restrict__ csr_src,
    const float* __restrict__ csr_norm, const float* __restrict__ selfw,
    const float* __restrict__ zin, const float* __restrict__ h,
    float* __restrict__ zout, int n)
{
    int idx = blockIdx.x * blockDim.x + threadIdx.x;
    int wid = idx >> 6;
    int lane = idx & 63;
    if (wid >= n) return;
    int beg = row_start[wid];
    int end = row_start[wid + 1];
    float a0 = 0.f, a1 = 0.f, a2 = 0.f, a3 = 0.f;
    int e = beg;
    for (; e + 3 < end; e += 4) {
        int s0 = csr_src[e], s1 = csr_src[e + 1], s2 = csr_src[e + 2], s3 = csr_src[e + 3];
        float w0 = csr_norm[e], w1 = csr_norm[e + 1], w2 = csr_norm[e + 2], w3 = csr_norm[e + 3];
        a0 += w0 * zin[(size_t)s0 * 64 + lane];
        a1 += w1 * zin[(size_t)s1 * 64 + lane];
        a2 += w2 * zin[(size_t)s2 * 64 + lane];
        a3 += w3 * zin[(size_t)s3 * 64 + lane];
    }
    for (; e < end; ++e) {
        int s = csr_src[e];
        a0 += csr_norm[e] * zin[(size_t)s * 64 + lane];
    }
    float acc = (a0 + a1) + (a2 + a3);
    float zi = zin[(size_t)wid * 64 + lane];
    float agg = acc + selfw[wid] * zi;
    zout[(size_t)wid * 64 + lane] = (1.0f - ALPHA) * agg + ALPHA * h[(size_t)wid * 64 + lane];
}

// ---------------------------------------------------------------- log_softmax over C=64 (wave per node)
__global__ __launch_bounds__(256) void logsoftmax_kernel(const float* __restrict__ z,
                                                         float* __restrict__ out, int n) {
    int idx = blockIdx.x * blockDim.x + threadIdx.x;
    int wid = idx >> 6;
    int lane = idx & 63;
    if (wid >= n) return;
    float v = z[(size_t)wid * 64 + lane];
    float m = v;
    #pragma unroll
    for (int off = 32; off > 0; off >>= 1) m = fmaxf(m, __shfl_xor(m, off));
    float ex = expf(v - m);
    float s = ex;
    #pragma unroll
    for (int off = 32; off > 0; off >>= 1) s += __shfl_xor(s, off);
    out[(size_t)wid * 64 + lane] = v - m - logf(s);
}

// ---------------------------------------------------------------- launch
extern "C" void kernel_launch(void* const* d_in, const int* in_sizes, int n_in,
                              void* d_out, int out_size, void* d_ws, size_t ws_size,
                              hipStream_t stream) {
    const float* x  = (const float*)d_in[0];
    const float* W1 = (const float*)d_in[1];
    const float* b1 = (const float*)d_in[2];
    const float* W2 = (const float*)d_in[3];
    const float* b2 = (const float*)d_in[4];
    const int*   ei = (const int*)d_in[5];
    const int* src = ei;
    const int* dst = ei + N_EDGES;
    float* out = (float*)d_out;

    char* ws = (char*)d_ws;
    size_t off = 0;
    auto alloc = [&](size_t bytes) -> void* {
        void* p = ws + off;
        off += (bytes + 255) & ~(size_t)255;
        return p;
    };
    int*   deg       = (int*)  alloc((size_t)N_NODES * 4);
    int*   cursor    = (int*)  alloc((size_t)N_NODES * 4);
    int*   row_start = (int*)  alloc((size_t)(N_NODES + 1) * 4);
    float* dinv      = (float*)alloc((size_t)N_NODES * 4);
    float* selfw     = (float*)alloc((size_t)N_NODES * 4);
    int*   csr_src   = (int*)  alloc((size_t)N_EDGES * 4);
    float* csr_norm  = (float*)alloc((size_t)N_EDGES * 4);
    float* h         = (float*)alloc((size_t)N_NODES * C_DIM * 4);
    float* za        = (float*)alloc((size_t)N_NODES * C_DIM * 4);
    float* zb        = (float*)alloc((size_t)N_NODES * C_DIM * 4);

    zero_kernel<<<(N_NODES + 255) / 256, 256, 0, stream>>>(deg, cursor, N_NODES);
    deg_kernel<<<(N_EDGES + 255) / 256, 256, 0, stream>>>(dst, deg, N_EDGES);
    dinv_kernel<<<(N_NODES + 255) / 256, 256, 0, stream>>>(deg, dinv, selfw, N_NODES);
    scan_kernel<<<1, 1024, 0, stream>>>(deg, row_start, N_NODES);
    scatter_kernel<<<(N_EDGES + 255) / 256, 256, 0, stream>>>(src, dst, row_start, cursor,
                                                              dinv, csr_src, csr_norm, N_EDGES);
    mlp_kernel<<<(N_NODES + 511) / 512, 256, 0, stream>>>(x, W1, b1, W2, b2, h, N_NODES);

    const float* zin = h;
    float* zout = za;
    for (int k = 0; k < K_STEPS; ++k) {
        appnp_kernel<<<(N_NODES * 64 + 255) / 256, 256, 0, stream>>>(
            row_start, csr_src, csr_norm, selfw, zin, h, zout, N_NODES);
        zin = zout;
        zout = (zout == za) ? zb : za;
    }
    logsoftmax_kernel<<<(N_NODES * 64 + 255) / 256, 256, 0, stream>>>(zin, out, N_NODES);
}